// Round 11
// baseline (55.084 us; speedup 1.0000x reference)
//
#include <hip/hip_runtime.h>

// Problem constants
#define NQ 20
#define DIMQ (1 << NQ)          // 2^20
#define NB 16                   // BATCH
#define NT 4                    // N_TERMS
#define RBITS 15                // low bits untouched by gates
#define NCOL (1 << (RBITS + 4)) // 2^15 r-values * 16 batches = 524288 columns

// U table layout in ws/LDS: per (k,b): 36 floats (16 complex interleaved + 4 pad)
//   base = (k*16 + b) * 36 ; entry (i,j): re at base + (i*4+j)*2, im at +1
//   36 floats = 144 B = 9*16 B -> every (k,b) base is 16B-aligned.
#define USTRIDE 36
#define UTOT (64 * USTRIDE)     // 2304 floats = 9216 B

// lane <-> lane^1 exchange as DPP quad_perm [1,0,3,2] (0xB1): pure VALU,
// no lgkmcnt wait, no ds-pipe traffic (vs __shfl_xor = ds_bpermute).
__device__ __forceinline__ float dpp_swap1(float x) {
  int xi = __builtin_bit_cast(int, x);
  int r  = __builtin_amdgcn_mov_dpp(xi, 0xB1, 0xF, 0xF, true);
  return __builtin_bit_cast(float, r);
}

// ---------------------------------------------------------------------------
// Kernel A: U[k,b] = exp(-i * H_k * t_{k,b}),  H_k = 0.5*(A + A^H), A = Hr + i Hi
// 256 threads: 64 tasks (k,b) x 4 rows. Scaling (2^-4) + 8-term Taylor +
// 4 squarings (trunc error ~(||H||t/16)^9/9! ~ 1e-10 -- invisible at fp32).
// ---------------------------------------------------------------------------
__global__ __launch_bounds__(256) void compute_u_kernel(
    const float* __restrict__ Hre, const float* __restrict__ Him,
    const float* __restrict__ tevo, float* __restrict__ uout) {
  __shared__ float er_s[64][4][4];
  __shared__ float ei_s[64][4][4];

  const int tid  = threadIdx.x;   // 0..255
  const int task = tid >> 2;      // 0..63
  const int row  = tid & 3;       // 0..3
  const int k    = task >> 4;     // 0..3
  const int b    = task & 15;     // 0..15

  float Ar[4][4], Ai[4][4];
#pragma unroll
  for (int i = 0; i < 4; i++) {
#pragma unroll
    for (int j = 0; j < 4; j++) {
      Ar[i][j] = Hre[k * 16 + i * 4 + j];
      Ai[i][j] = Him[k * 16 + i * 4 + j];
    }
  }
  const float t = tevo[k * NB + b];
  const float ts = t * (1.0f / 16.0f);  // scale 2^-4 folded in

  // G = -i * H * ts ; H = 0.5*(A + A^H)
  float Gr[4][4], Gi[4][4];
#pragma unroll
  for (int i = 0; i < 4; i++) {
#pragma unroll
    for (int j = 0; j < 4; j++) {
      const float hr = 0.5f * (Ar[i][j] + Ar[j][i]);
      const float hi = 0.5f * (Ai[i][j] - Ai[j][i]);
      Gr[i][j] = ts * hi;
      Gi[i][j] = -ts * hr;
    }
  }

  // Taylor: E = I + sum_{m=1..8} G^m/m!   (row `row` only; full G in regs)
  float Er[4], Ei[4], Tr[4], Ti[4];
#pragma unroll
  for (int j = 0; j < 4; j++) {
    Er[j] = (j == row) ? 1.0f : 0.0f;
    Ei[j] = 0.0f;
    Tr[j] = Er[j];
    Ti[j] = 0.0f;
  }
#pragma unroll
  for (int m = 1; m <= 8; m++) {
    const float inv = 1.0f / (float)m;
    float nr[4], ni[4];
#pragma unroll
    for (int j = 0; j < 4; j++) {
      float ar = 0.0f, ai = 0.0f;
#pragma unroll
      for (int p = 0; p < 4; p++) {
        ar += Tr[p] * Gr[p][j] - Ti[p] * Gi[p][j];
        ai += Tr[p] * Gi[p][j] + Ti[p] * Gr[p][j];
      }
      nr[j] = ar * inv;
      ni[j] = ai * inv;
    }
#pragma unroll
    for (int j = 0; j < 4; j++) {
      Tr[j] = nr[j]; Ti[j] = ni[j];
      Er[j] += nr[j]; Ei[j] += ni[j];
    }
  }

  // 4 squarings via LDS (uniform trip count -> barriers are safe)
  for (int q = 0; q < 4; q++) {
    __syncthreads();
#pragma unroll
    for (int j = 0; j < 4; j++) {
      er_s[task][row][j] = Er[j];
      ei_s[task][row][j] = Ei[j];
    }
    __syncthreads();
    float nr[4], ni[4];
#pragma unroll
    for (int j = 0; j < 4; j++) {
      float ar = 0.0f, ai = 0.0f;
#pragma unroll
      for (int p = 0; p < 4; p++) {
        ar += Er[p] * er_s[task][p][j] - Ei[p] * ei_s[task][p][j];
        ai += Er[p] * ei_s[task][p][j] + Ei[p] * er_s[task][p][j];
      }
      nr[j] = ar; ni[j] = ai;
    }
#pragma unroll
    for (int j = 0; j < 4; j++) { Er[j] = nr[j]; Ei[j] = ni[j]; }
  }

  // Store U rows: layout [k][b][16 complex interleaved], row stride 36 floats
  const int ubase = (k * 16 + b) * USTRIDE;
#pragma unroll
  for (int j = 0; j < 4; j++) {
    uout[ubase + (row * 4 + j) * 2]     = Er[j];
    uout[ubase + (row * 4 + j) * 2 + 1] = Ei[j];
  }
}

// ---------------------------------------------------------------------------
// Kernel B (r10 core, state loads hoisted above the U-stage barrier):
// two ADJACENT LANES per column (r,b); each owns one 16-g half.
//   half = tid&1, col = blockIdx*128 + (tid>>1), b = (tid>>1)&15.
// Order: (1) issue all 32 state loads (HBM latency starts ticking),
//        (2) stage the 9 KiB U table to LDS, (3) __syncthreads -- its
//            vmcnt(0) drain completes the state loads INTO REGISTERS and
//            prevents the allocator folding them into uses (no sinking
//            across a barrier), (4) pure-VALU compute stream.
// Gates k=1..3 are half-local; k=0 cross term exchanged via DPP quad_perm.
// ---------------------------------------------------------------------------
__global__ __launch_bounds__(256, 4) void apply_gates_kernel(
    const float* __restrict__ sre, const float* __restrict__ sim,
    const float* __restrict__ u, float* __restrict__ out) {
  __shared__ __align__(16) float ul[UTOT];
  const int tid   = threadIdx.x;
  const int half  = tid & 1;                        // lanes alternate halves
  const int col   = blockIdx.x * 128 + (tid >> 1);  // r*16 + b
  const int b     = (tid >> 1) & 15;
  const int gbase = half << 4;

  // (1) own half: 16 complex -- one burst of 32 dword loads, issued FIRST
  float s_re[16], s_im[16];
#pragma unroll
  for (int q = 0; q < 16; q++) {
    const int off = col + ((gbase + q) << 19);
    s_re[q] = sre[off];
    s_im[q] = sim[off];
  }

  // (2) stage U table (9 KiB) to LDS; UTOT = 9*256 exactly
#pragma unroll
  for (int q = 0; q < 9; q++) ul[tid + q * 256] = u[tid + q * 256];
  // (3) barrier: drains U writes AND the state-load burst into registers
  __syncthreads();

  float o_re[16], o_im[16];

  // ---- k = 0 (g bits [4:3]) : own term + DPP-exchanged cross term ----
  // own output g = half<<4 | b3<<3 | l : row i = 2*half + b3.
  // own sources s_re[l] (j=2*half), s_re[8+l] (j=2*half+1).
  // cross partial: contribution of MY sources (same j) to partner output
  // with row i' = 2*(half^1) + b3; partner adds the swapped value.
  {
    const float* ub0 = &ul[b * USTRIDE];  // k = 0 block
    const int h4 = half * 4;              // float offset of (j=2h) entry pair
#pragma unroll
    for (int b3 = 0; b3 < 2; b3++) {
      const float4 vo = *(const float4*)(ub0 + (half * 2 + b3) * 8 + h4);
      const float4 vc = *(const float4*)(ub0 + ((half ^ 1) * 2 + b3) * 8 + h4);
#pragma unroll
      for (int l = 0; l < 8; l++) {
        const int gq = b3 * 8 + l;
        o_re[gq] = vo.x * s_re[l]     - vo.y * s_im[l]
                 + vo.z * s_re[8 + l] - vo.w * s_im[8 + l];
        o_im[gq] = vo.x * s_im[l]     + vo.y * s_re[l]
                 + vo.z * s_im[8 + l] + vo.w * s_re[8 + l];
        float pr = vc.x * s_re[l]     - vc.y * s_im[l]
                 + vc.z * s_re[8 + l] - vc.w * s_im[8 + l];
        float pi = vc.x * s_im[l]     + vc.y * s_re[l]
                 + vc.z * s_im[8 + l] + vc.w * s_re[8 + l];
        o_re[gq] += dpp_swap1(pr);
        o_im[gq] += dpp_swap1(pi);
      }
    }
  }

  // ---- k = 1..3: fully local to the half (bits [3:0] of g) ----
#pragma unroll
  for (int k = 1; k < 4; k++) {
    const int sh = 3 - k;  // 2, 1, 0
    const float* ub = &ul[(k * 16 + b) * USTRIDE];
#pragma unroll
    for (int i = 0; i < 4; i++) {
      const float4 v0 = *(const float4*)(ub + i * 8);      // j=0,1
      const float4 v1 = *(const float4*)(ub + i * 8 + 4);  // j=2,3
#pragma unroll
      for (int qq = 0; qq < 4; qq++) {
        const int low  = qq & ((1 << sh) - 1);
        const int high = (qq >> sh) << (sh + 2);
        const int gb   = high | low;           // gq with pair bits cleared
        const int gq   = gb | (i << sh);
        const int s0 = gb;
        const int s1 = gb | (1 << sh);
        const int s2 = gb | (2 << sh);
        const int s3 = gb | (3 << sh);
        o_re[gq] += v0.x * s_re[s0] - v0.y * s_im[s0]
                  + v0.z * s_re[s1] - v0.w * s_im[s1]
                  + v1.x * s_re[s2] - v1.y * s_im[s2]
                  + v1.z * s_re[s3] - v1.w * s_im[s3];
        o_im[gq] += v0.x * s_im[s0] + v0.y * s_re[s0]
                  + v0.z * s_im[s1] + v0.w * s_re[s1]
                  + v1.x * s_im[s2] + v1.y * s_re[s2]
                  + v1.z * s_im[s3] + v1.w * s_re[s3];
      }
    }
  }

#pragma unroll
  for (int q = 0; q < 16; q++) {
    const int off = col + ((gbase + q) << 19);
    __builtin_nontemporal_store(o_re[q], out + off);               // real
    __builtin_nontemporal_store(o_im[q], out + off + (1 << 24));   // imag
  }
}

extern "C" void kernel_launch(void* const* d_in, const int* in_sizes, int n_in,
                              void* d_out, int out_size, void* d_ws, size_t ws_size,
                              hipStream_t stream) {
  const float* Hre  = (const float*)d_in[0];
  const float* Him  = (const float*)d_in[1];
  const float* tevo = (const float*)d_in[2];
  const float* sre  = (const float*)d_in[3];
  const float* sim  = (const float*)d_in[4];
  float* out = (float*)d_out;
  float* uws = (float*)d_ws;  // UTOT floats = 9216 B

  compute_u_kernel<<<1, 256, 0, stream>>>(Hre, Him, tevo, uws);
  apply_gates_kernel<<<NCOL / 128, 256, 0, stream>>>(sre, sim, uws, out);
}